// Round 1
// baseline (216.908 us; speedup 1.0000x reference)
//
#include <hip/hip_runtime.h>
#include <hip/hip_bf16.h>

#define SENTINEL 24635

using bf16x8  = __attribute__((ext_vector_type(8))) __bf16;
using floatx4 = __attribute__((ext_vector_type(4))) float;

__device__ inline bf16x8 cvt8(float4 a, float4 b) {
  bf16x8 v;
  v[0] = (__bf16)a.x; v[1] = (__bf16)a.y; v[2] = (__bf16)a.z; v[3] = (__bf16)a.w;
  v[4] = (__bf16)b.x; v[5] = (__bf16)b.y; v[6] = (__bf16)b.z; v[7] = (__bf16)b.w;
  return v;
}

// ---------------------------------------------------------------------------
// Pool: user_embs[b] = masked mean of ent_embs[ent_list[b, :cnt]] (prefix-valid
// until first SENTINEL); cnt==0 -> ent_embs[SENTINEL]. fp32 throughout.
// grid 4096 blocks x 128 threads (one thread per dim).
// ---------------------------------------------------------------------------
__global__ void pool_kernel(const float* __restrict__ ent_embs,
                            const int* __restrict__ ent_list,
                            float* __restrict__ user) {
  const int b = blockIdx.x;
  const int d = threadIdx.x;
  const int* lst = ent_list + b * 50;
  // pass 1: find count (uniform across block)
  int cnt = 0;
  for (int l = 0; l < 50; ++l) {
    if (lst[l] == SENTINEL) break;
    ++cnt;
  }
  float sum = 0.f;
  for (int l = 0; l < cnt; ++l) {
    sum += ent_embs[(size_t)lst[l] * 128 + d];
  }
  float v = (cnt == 0) ? ent_embs[(size_t)SENTINEL * 128 + d]
                       : sum / (float)cnt;
  user[(size_t)b * 128 + d] = v;
}

// ---------------------------------------------------------------------------
// GEMM: C[m][n] = act( sum_k A[m][k] * W[n][k] )  (both row-major, contiguous K)
// bf16 MFMA 16x16x32, fp32 accumulate. 64x64 tile, BK=32, 256 threads (4 waves),
// wave w computes rows w*16..w*16+15 x all 64 cols (4 col tiles).
// LDS rows padded to 40 bf16 (80 B): lane bank = (row*20 + quad*4) % 32 -> 2-way
// conflict only (free per m136); 80 B stride keeps 16 B alignment for b128 reads.
// Requires M%64==0, N%64==0, K%32==0 (true here: 4096 x {768,512,128} x {1024,768,512}).
// ---------------------------------------------------------------------------
template <int RELU>
__global__ __launch_bounds__(256) void gemm_nt(const float* __restrict__ A,
                                               const float* __restrict__ W,
                                               float* __restrict__ C,
                                               int M, int N, int K) {
  __shared__ __bf16 As[64][40];
  __shared__ __bf16 Bs[64][40];
  const int bn0 = blockIdx.x * 64;
  const int bm0 = blockIdx.y * 64;
  const int tid  = threadIdx.x;
  const int w    = tid >> 6;
  const int lane = tid & 63;
  const int quad = lane >> 4;
  const int l16  = lane & 15;
  const int srow = tid >> 2;        // 0..63
  const int scol = (tid & 3) << 3;  // 0,8,16,24
  const float* Ap = A + (size_t)(bm0 + srow) * K + scol;
  const float* Wp = W + (size_t)(bn0 + srow) * K + scol;

  floatx4 acc[4];
#pragma unroll
  for (int t = 0; t < 4; ++t) acc[t] = (floatx4){0.f, 0.f, 0.f, 0.f};

  for (int k0 = 0; k0 < K; k0 += 32) {
    __syncthreads();
    float4 a0 = *(const float4*)(Ap + k0);
    float4 a1 = *(const float4*)(Ap + k0 + 4);
    float4 b0 = *(const float4*)(Wp + k0);
    float4 b1 = *(const float4*)(Wp + k0 + 4);
    *(bf16x8*)&As[srow][scol] = cvt8(a0, a1);
    *(bf16x8*)&Bs[srow][scol] = cvt8(b0, b1);
    __syncthreads();
    bf16x8 af = *(const bf16x8*)&As[w * 16 + l16][quad * 8];
#pragma unroll
    for (int t = 0; t < 4; ++t) {
      bf16x8 bf = *(const bf16x8*)&Bs[t * 16 + l16][quad * 8];
      acc[t] = __builtin_amdgcn_mfma_f32_16x16x32_bf16(af, bf, acc[t], 0, 0, 0);
    }
  }

  const int row = bm0 + w * 16 + quad * 4;
#pragma unroll
  for (int t = 0; t < 4; ++t) {
#pragma unroll
    for (int r = 0; r < 4; ++r) {
      float v = acc[t][r];
      if (RELU) v = v > 0.f ? v : 0.f;
      C[(size_t)(row + r) * N + bn0 + t * 16 + l16] = v;
    }
  }
}

// ---------------------------------------------------------------------------
// Flash-ish attention WITHOUT max-subtraction (scores ~1e-3, exp is safe):
//   O_part[split] = sum_{chunks in split} exp(Q Uc^T * scale) @ Uc  (fp32 acc)
//   l_part[split] = row sums of exp(...)
// Block: 256 threads (4 waves), 64 query rows; grid (4096/64, 4 key-splits).
// QK: A=Q (bf16 frags held in regs), B=U chunk (normal LDS layout).
// PV: A=P via LDS round-trip (C-layout -> A-layout), B=U chunk transposed LDS.
// ---------------------------------------------------------------------------
__global__ __launch_bounds__(256) void flash_attn(const float* __restrict__ Q,
                                                  const float* __restrict__ U,
                                                  float* __restrict__ O_part,
                                                  float* __restrict__ l_part) {
  __shared__ __bf16 Un[64][136];   // U chunk [key][d], pad 136 -> 2-way banks
  __shared__ __bf16 Ut[128][72];   // U chunk transposed [d][key], pad 72
  __shared__ __bf16 Ps[4][16][72]; // per-wave P tile [row][key], pad 72
  const int tid  = threadIdx.x;
  const int w    = tid >> 6;
  const int lane = tid & 63;
  const int quad = lane >> 4;
  const int l16  = lane & 15;
  const int qrow0 = blockIdx.x * 64;
  const int split = blockIdx.y;
  const float scale = 0.08838834764831845f;  // 1/sqrt(128)

  // Stage Q (fp32 -> bf16) into Un, pull per-wave A-fragments into registers.
  for (int i = tid; i < 1024; i += 256) {
    int r = i >> 4, c = (i & 15) << 3;
    const float* p = Q + (size_t)(qrow0 + r) * 128 + c;
    float4 x0 = *(const float4*)p;
    float4 x1 = *(const float4*)(p + 4);
    *(bf16x8*)&Un[r][c] = cvt8(x0, x1);
  }
  __syncthreads();
  bf16x8 aq[4];
#pragma unroll
  for (int c = 0; c < 4; ++c)
    aq[c] = *(const bf16x8*)&Un[w * 16 + l16][c * 32 + quad * 8];

  floatx4 o[8];
#pragma unroll
  for (int t = 0; t < 8; ++t) o[t] = (floatx4){0.f, 0.f, 0.f, 0.f};
  float lsum[4] = {0.f, 0.f, 0.f, 0.f};

  for (int chunk = 0; chunk < 16; ++chunk) {
    const int key0 = split * 1024 + chunk * 64;
    __syncthreads();  // protect Un/Ut against prior-iteration readers
    for (int i = tid; i < 1024; i += 256) {
      int r = i >> 4, c = (i & 15) << 3;
      const float* p = U + (size_t)(key0 + r) * 128 + c;
      float4 x0 = *(const float4*)p;
      float4 x1 = *(const float4*)(p + 4);
      bf16x8 v = cvt8(x0, x1);
      *(bf16x8*)&Un[r][c] = v;
#pragma unroll
      for (int j = 0; j < 8; ++j) Ut[c + j][r] = v[j];
    }
    __syncthreads();

    // QK^T -> exp -> P (bf16) to LDS; accumulate fp32 row sums.
#pragma unroll
    for (int t = 0; t < 4; ++t) {
      floatx4 s = (floatx4){0.f, 0.f, 0.f, 0.f};
#pragma unroll
      for (int c = 0; c < 4; ++c) {
        bf16x8 bk = *(const bf16x8*)&Un[t * 16 + l16][c * 32 + quad * 8];
        s = __builtin_amdgcn_mfma_f32_16x16x32_bf16(aq[c], bk, s, 0, 0, 0);
      }
#pragma unroll
      for (int r = 0; r < 4; ++r) {
        float pv = __expf(s[r] * scale);
        lsum[r] += pv;
        Ps[w][quad * 4 + r][t * 16 + l16] = (__bf16)pv;
      }
    }
    __syncthreads();  // P visible (also orders Ut reads below vs staging)

    // PV: O += P @ Uc
#pragma unroll
    for (int c = 0; c < 2; ++c) {
      bf16x8 ap = *(const bf16x8*)&Ps[w][l16][c * 32 + quad * 8];
#pragma unroll
      for (int dt = 0; dt < 8; ++dt) {
        bf16x8 bv = *(const bf16x8*)&Ut[dt * 16 + l16][c * 32 + quad * 8];
        o[dt] = __builtin_amdgcn_mfma_f32_16x16x32_bf16(ap, bv, o[dt], 0, 0, 0);
      }
    }
  }

  // Reduce lsum across the 16 lanes of each quad-row group (cols partition).
#pragma unroll
  for (int r = 0; r < 4; ++r) {
    float v = lsum[r];
    v += __shfl_xor(v, 1);
    v += __shfl_xor(v, 2);
    v += __shfl_xor(v, 4);
    v += __shfl_xor(v, 8);
    lsum[r] = v;
  }

  const int row0 = qrow0 + w * 16 + quad * 4;
  float* Ob = O_part + (size_t)split * 4096 * 128;
#pragma unroll
  for (int dt = 0; dt < 8; ++dt) {
#pragma unroll
    for (int r = 0; r < 4; ++r) {
      Ob[(size_t)(row0 + r) * 128 + dt * 16 + l16] = o[dt][r];
    }
  }
  if (l16 == 0) {
#pragma unroll
    for (int r = 0; r < 4; ++r) l_part[split * 4096 + row0 + r] = lsum[r];
  }
}

// ---------------------------------------------------------------------------
// Combine the 4 key-splits: out = (sum_s O_s) / (sum_s l_s)
// ---------------------------------------------------------------------------
__global__ void combine_kernel(const float* __restrict__ O_part,
                               const float* __restrict__ l_part,
                               float* __restrict__ out) {
  const int i = blockIdx.x * 256 + threadIdx.x;  // 0 .. 4096*128-1
  const int row = i >> 7;
  float num = 0.f, den = 0.f;
#pragma unroll
  for (int s = 0; s < 4; ++s) {
    num += O_part[(size_t)s * 4096 * 128 + i];
    den += l_part[s * 4096 + row];
  }
  out[i] = num / den;
}

extern "C" void kernel_launch(void* const* d_in, const int* in_sizes, int n_in,
                              void* d_out, int out_size, void* d_ws, size_t ws_size,
                              hipStream_t stream) {
  (void)in_sizes; (void)n_in; (void)out_size; (void)ws_size;
  const float* ctx      = (const float*)d_in[0];  // [4096,1024]
  const float* ent_embs = (const float*)d_in[1];  // [24636,128]
  const float* W1       = (const float*)d_in[2];  // [768,1024]
  const float* W2       = (const float*)d_in[3];  // [512,768]
  const float* W3       = (const float*)d_in[4];  // [128,512]
  const int*   ent_list = (const int*)d_in[5];    // [4096,50]
  float* out = (float*)d_out;

  // ws layout (floats). O_part/l_part reuse x1's region (dead after gemm2).
  float* ws     = (float*)d_ws;
  float* user   = ws;                       // 524288
  float* q      = ws + 524288;              // 524288
  float* x1     = ws + 1048576;             // 3145728
  float* x2     = ws + 4194304;             // 2097152 (peak: 25.2 MB)
  float* O_part = ws + 1048576;             // 4*524288 (overlaps dead x1)
  float* l_part = ws + 1048576 + 2097152;   // 4*4096   (still inside x1 region)

  pool_kernel<<<4096, 128, 0, stream>>>(ent_embs, ent_list, user);
  gemm_nt<1><<<dim3(12, 64), 256, 0, stream>>>(ctx, W1, x1, 4096, 768, 1024);
  gemm_nt<1><<<dim3(8, 64), 256, 0, stream>>>(x1, W2, x2, 4096, 512, 768);
  gemm_nt<0><<<dim3(2, 64), 256, 0, stream>>>(x2, W3, q, 4096, 128, 512);
  flash_attn<<<dim3(64, 4), 256, 0, stream>>>(q, user, O_part, l_part);
  combine_kernel<<<2048, 256, 0, stream>>>(O_part, l_part, out);
}

// Round 2
// 214.284 us; speedup vs baseline: 1.0122x; 1.0122x over previous
//
#include <hip/hip_runtime.h>
#include <hip/hip_bf16.h>

#define SENTINEL 24635

using bf16x8  = __attribute__((ext_vector_type(8))) __bf16;
using bf16x2  = __attribute__((ext_vector_type(2))) __bf16;
using floatx4 = __attribute__((ext_vector_type(4))) float;

__device__ inline bf16x8 cvt8(float4 a, float4 b) {
  bf16x8 v;
  v[0] = (__bf16)a.x; v[1] = (__bf16)a.y; v[2] = (__bf16)a.z; v[3] = (__bf16)a.w;
  v[4] = (__bf16)b.x; v[5] = (__bf16)b.y; v[6] = (__bf16)b.z; v[7] = (__bf16)b.w;
  return v;
}

// ---------------------------------------------------------------------------
// f32 -> bf16 elementwise convert (for W1/W2/W3), 8 elements/thread.
// ---------------------------------------------------------------------------
__global__ void cvt_kernel(const float* __restrict__ in, __bf16* __restrict__ out,
                           int n) {
  int i = (blockIdx.x * 256 + threadIdx.x) * 8;
  if (i < n) {
    float4 a = *(const float4*)(in + i);
    float4 b = *(const float4*)(in + i + 4);
    *(bf16x8*)(out + i) = cvt8(a, b);
  }
}

// ---------------------------------------------------------------------------
// Pool: user_n[b] = bf16( masked mean of ent_embs[ent_list[b,:cnt]] ),
// cnt = index of first SENTINEL (prefix-valid); cnt==0 -> ent_embs[SENTINEL].
// One wave per row; lane covers dims {2*lane, 2*lane+1}. cnt via ballot;
// gather loads are independent (no sequential break) so they overlap.
// ---------------------------------------------------------------------------
__global__ __launch_bounds__(64) void pool_kernel(const float* __restrict__ ent,
                                                  const int* __restrict__ ent_list,
                                                  __bf16* __restrict__ user_n) {
  const int b = blockIdx.x;
  const int lane = threadIdx.x;
  int myidx = (lane < 50) ? ent_list[b * 50 + lane] : 0;
  unsigned long long m = __ballot(lane < 50 && myidx == SENTINEL);
  const int cnt = (m == 0) ? 50 : (int)__builtin_ctzll(m);

  float sx = 0.f, sy = 0.f;
  for (int l = 0; l < cnt; ++l) {
    int idx = __shfl(myidx, l);
    float2 e = *(const float2*)(ent + (size_t)idx * 128 + lane * 2);
    sx += e.x; sy += e.y;
  }
  float vx, vy;
  if (cnt == 0) {
    float2 e = *(const float2*)(ent + (size_t)SENTINEL * 128 + lane * 2);
    vx = e.x; vy = e.y;
  } else {
    float inv = 1.f / (float)cnt;
    vx = sx * inv; vy = sy * inv;
  }
  bf16x2 o; o[0] = (__bf16)vx; o[1] = (__bf16)vy;
  *(bf16x2*)(user_n + (size_t)b * 128 + lane * 2) = o;
}

// ---------------------------------------------------------------------------
// Transpose user_n [4096][128] bf16 -> user_t [128][4096] bf16 via LDS tiles.
// grid (64, 2), 256 threads, 64x64 tiles.
// ---------------------------------------------------------------------------
__global__ __launch_bounds__(256) void transpose_kernel(const __bf16* __restrict__ in,
                                                        __bf16* __restrict__ out) {
  __shared__ __bf16 T[64][72];  // 144 B stride: 16B-aligned rows
  const int r0 = blockIdx.x * 64;   // key rows
  const int c0 = blockIdx.y * 64;   // dim cols
  const int tid = threadIdx.x;
#pragma unroll
  for (int p = 0; p < 2; ++p) {
    int r = (tid >> 3) + p * 32;
    int c = (tid & 7) * 8;
    *(bf16x8*)&T[r][c] = *(const bf16x8*)(in + (size_t)(r0 + r) * 128 + c0 + c);
  }
  __syncthreads();
#pragma unroll
  for (int p = 0; p < 2; ++p) {
    int c = (tid >> 3) + p * 32;   // dim within tile
    int r = (tid & 7) * 8;         // key base within tile
    bf16x8 v;
#pragma unroll
    for (int j = 0; j < 8; ++j) v[j] = T[r + j][c];
    *(bf16x8*)(out + (size_t)(c0 + c) * 4096 + r0 + r) = v;
  }
}

// ---------------------------------------------------------------------------
// GEMM: C[m][n] = bf16( act( sum_k A[m][k] * W[n][k] ) )
// A: float (fused convert) or __bf16. W: __bf16 (preconverted). C: __bf16.
// Tile BM x 128 (BM = MT*32), BK=32, 256 threads, 4 waves in 2x2.
// Wave (wr,wc) computes rows wr*MT*16 + mt*16, cols wc*64 + nt*16.
// LDS rows padded to 40 bf16 (80 B): 2-way banks only (free per m136).
// Requires M%BM==0, N%128==0, K%32==0.
// ---------------------------------------------------------------------------
template <typename AT, int MT, int RELU>
__global__ __launch_bounds__(256) void gemm_bt(const AT* __restrict__ A,
                                               const __bf16* __restrict__ W,
                                               __bf16* __restrict__ C,
                                               int M, int N, int K) {
  constexpr int BM = MT * 32;
  __shared__ __bf16 As[BM][40];
  __shared__ __bf16 Bs[128][40];
  const int bn0 = blockIdx.x * 128;
  const int bm0 = blockIdx.y * BM;
  const int tid  = threadIdx.x;
  const int w    = tid >> 6;
  const int lane = tid & 63;
  const int quad = lane >> 4;
  const int l16  = lane & 15;
  const int wr   = w >> 1;
  const int wc   = w & 1;
  const int srow = tid >> 2;          // 0..63
  const int scol = (tid & 3) * 8;     // 0,8,16,24

  floatx4 acc[MT][4];
#pragma unroll
  for (int mt = 0; mt < MT; ++mt)
#pragma unroll
    for (int nt = 0; nt < 4; ++nt) acc[mt][nt] = (floatx4){0.f, 0.f, 0.f, 0.f};

  for (int k0 = 0; k0 < K; k0 += 32) {
    __syncthreads();
#pragma unroll
    for (int p = 0; p < BM / 64; ++p) {
      int r = srow + p * 64;
      const AT* ap = A + (size_t)(bm0 + r) * K + k0 + scol;
      if constexpr (__is_same(AT, float)) {
        float4 a0 = *(const float4*)ap;
        float4 a1 = *(const float4*)(ap + 4);
        *(bf16x8*)&As[r][scol] = cvt8(a0, a1);
      } else {
        *(bf16x8*)&As[r][scol] = *(const bf16x8*)ap;
      }
    }
#pragma unroll
    for (int p = 0; p < 2; ++p) {
      int r = srow + p * 64;
      *(bf16x8*)&Bs[r][scol] =
          *(const bf16x8*)(W + (size_t)(bn0 + r) * K + k0 + scol);
    }
    __syncthreads();
    bf16x8 af[MT], bfr[4];
#pragma unroll
    for (int mt = 0; mt < MT; ++mt)
      af[mt] = *(const bf16x8*)&As[wr * (MT * 16) + mt * 16 + l16][quad * 8];
#pragma unroll
    for (int nt = 0; nt < 4; ++nt)
      bfr[nt] = *(const bf16x8*)&Bs[wc * 64 + nt * 16 + l16][quad * 8];
#pragma unroll
    for (int mt = 0; mt < MT; ++mt)
#pragma unroll
      for (int nt = 0; nt < 4; ++nt)
        acc[mt][nt] =
            __builtin_amdgcn_mfma_f32_16x16x32_bf16(af[mt], bfr[nt], acc[mt][nt], 0, 0, 0);
  }

#pragma unroll
  for (int mt = 0; mt < MT; ++mt) {
    const int row0 = bm0 + wr * (MT * 16) + mt * 16 + quad * 4;
#pragma unroll
    for (int nt = 0; nt < 4; ++nt) {
      const int col = bn0 + wc * 64 + nt * 16 + l16;
#pragma unroll
      for (int r = 0; r < 4; ++r) {
        float v = acc[mt][nt][r];
        if (RELU) v = v > 0.f ? v : 0.f;
        C[(size_t)(row0 + r) * N + col] = (__bf16)v;
      }
    }
  }
}

// ---------------------------------------------------------------------------
// Flash attention, no max-subtraction (|scores| ~ 1e-2: exp is safe):
//   O_part[split] = sum_chunks exp(Q Uc^T * scale) @ Uc ; l_part = row sums.
// grid (64 q-tiles, 8 key-splits) = 512 blocks (2/CU), 256 threads.
// All inputs bf16, pre-transposed: staging is pure b128 load->store.
// ---------------------------------------------------------------------------
__global__ __launch_bounds__(256) void flash_attn(const __bf16* __restrict__ Q,
                                                  const __bf16* __restrict__ Un_g,
                                                  const __bf16* __restrict__ Ut_g,
                                                  float* __restrict__ O_part,
                                                  float* __restrict__ l_part) {
  __shared__ __bf16 Un[64][136];   // [key][d]  stride 272 B (16B-mult, 2-way banks)
  __shared__ __bf16 Ut[128][72];   // [d][key]  stride 144 B
  __shared__ __bf16 Ps[4][16][72]; // per-wave P [qrow][key]
  const int tid  = threadIdx.x;
  const int w    = tid >> 6;
  const int lane = tid & 63;
  const int quad = lane >> 4;
  const int l16  = lane & 15;
  const int qrow0 = blockIdx.x * 64;
  const int split = blockIdx.y;
  const float scale = 0.08838834764831845f;  // 1/sqrt(128)

  // Q A-fragments straight from global (read-once, L2-served).
  bf16x8 aq[4];
#pragma unroll
  for (int c = 0; c < 4; ++c)
    aq[c] = *(const bf16x8*)(Q + (size_t)(qrow0 + w * 16 + l16) * 128 + c * 32 + quad * 8);

  floatx4 o[8];
#pragma unroll
  for (int t = 0; t < 8; ++t) o[t] = (floatx4){0.f, 0.f, 0.f, 0.f};
  float lsum[4] = {0.f, 0.f, 0.f, 0.f};

  for (int chunk = 0; chunk < 8; ++chunk) {
    const int key0 = split * 512 + chunk * 64;
    __syncthreads();  // protect Un/Ut vs prior iteration's readers
#pragma unroll
    for (int p = 0; p < 4; ++p) {   // Un: 64 keys x 128 d
      int r = (tid >> 4) + p * 16;
      int c = (tid & 15) * 8;
      *(bf16x8*)&Un[r][c] = *(const bf16x8*)(Un_g + (size_t)(key0 + r) * 128 + c);
    }
#pragma unroll
    for (int p = 0; p < 4; ++p) {   // Ut: 128 d x 64 keys
      int d = (tid >> 3) + p * 32;
      int kk = (tid & 7) * 8;
      *(bf16x8*)&Ut[d][kk] = *(const bf16x8*)(Ut_g + (size_t)d * 4096 + key0 + kk);
    }
    __syncthreads();

    // S = Q Uc^T (C-layout), exp in fp32, P -> LDS (bf16), fp32 row sums.
#pragma unroll
    for (int t = 0; t < 4; ++t) {
      floatx4 s = (floatx4){0.f, 0.f, 0.f, 0.f};
#pragma unroll
      for (int c = 0; c < 4; ++c) {
        bf16x8 bk = *(const bf16x8*)&Un[t * 16 + l16][c * 32 + quad * 8];
        s = __builtin_amdgcn_mfma_f32_16x16x32_bf16(aq[c], bk, s, 0, 0, 0);
      }
#pragma unroll
      for (int r = 0; r < 4; ++r) {
        float pv = __expf(s[r] * scale);
        lsum[r] += pv;
        Ps[w][quad * 4 + r][t * 16 + l16] = (__bf16)pv;
      }
    }
    __syncthreads();

    // O += P @ Uc
#pragma unroll
    for (int c = 0; c < 2; ++c) {
      bf16x8 ap = *(const bf16x8*)&Ps[w][l16][c * 32 + quad * 8];
#pragma unroll
      for (int dt = 0; dt < 8; ++dt) {
        bf16x8 bv = *(const bf16x8*)&Ut[dt * 16 + l16][c * 32 + quad * 8];
        o[dt] = __builtin_amdgcn_mfma_f32_16x16x32_bf16(ap, bv, o[dt], 0, 0, 0);
      }
    }
  }

  // Row sums: reduce over the 16 key-columns held across l16 (stay in quad).
#pragma unroll
  for (int r = 0; r < 4; ++r) {
    float v = lsum[r];
    v += __shfl_xor(v, 1);
    v += __shfl_xor(v, 2);
    v += __shfl_xor(v, 4);
    v += __shfl_xor(v, 8);
    lsum[r] = v;
  }

  const int row0 = qrow0 + w * 16 + quad * 4;
  float* Ob = O_part + (size_t)split * 4096 * 128;
#pragma unroll
  for (int dt = 0; dt < 8; ++dt) {
#pragma unroll
    for (int r = 0; r < 4; ++r) {
      Ob[(size_t)(row0 + r) * 128 + dt * 16 + l16] = o[dt][r];
    }
  }
  if (l16 == 0) {
#pragma unroll
    for (int r = 0; r < 4; ++r) l_part[split * 4096 + row0 + r] = lsum[r];
  }
}

// ---------------------------------------------------------------------------
// Combine 8 key-splits: out = (sum_s O_s) / (sum_s l_s)
// ---------------------------------------------------------------------------
__global__ void combine_kernel(const float* __restrict__ O_part,
                               const float* __restrict__ l_part,
                               float* __restrict__ out) {
  const int i = blockIdx.x * 256 + threadIdx.x;  // 0 .. 524287
  const int row = i >> 7;
  float num = 0.f, den = 0.f;
#pragma unroll
  for (int s = 0; s < 8; ++s) {
    num += O_part[(size_t)s * 524288 + i];
    den += l_part[s * 4096 + row];
  }
  out[i] = num / den;
}

extern "C" void kernel_launch(void* const* d_in, const int* in_sizes, int n_in,
                              void* d_out, int out_size, void* d_ws, size_t ws_size,
                              hipStream_t stream) {
  (void)in_sizes; (void)n_in; (void)out_size; (void)ws_size;
  const float* ctx      = (const float*)d_in[0];  // [4096,1024]
  const float* ent_embs = (const float*)d_in[1];  // [24636,128]
  const float* W1       = (const float*)d_in[2];  // [768,1024]
  const float* W2       = (const float*)d_in[3];  // [512,768]
  const float* W3       = (const float*)d_in[4];  // [128,512]
  const int*   ent_list = (const int*)d_in[5];    // [4096,50]
  float* out = (float*)d_out;

  // ws layout (bytes). O_part (16 MB) overlays x2b+x1b, both dead by flash.
  char* base = (char*)d_ws;
  __bf16* user_n = (__bf16*)(base);                    // 1 MB   [pool -> flash]
  __bf16* user_t = (__bf16*)(base + (1u << 20));       // 1 MB   [transpose -> flash]
  __bf16* qb     = (__bf16*)(base + (2u << 20));       // 1 MB   [gemm3 -> flash]
  float*  l_part = (float*)(base + (3u << 20));        // 128 KB
  __bf16* W1b    = (__bf16*)(base + 3407872u);         // 3.25 MB, 1.5 MB
  __bf16* W2b    = (__bf16*)(base + 4980736u);         // 4.75 MB, 0.75 MB
  __bf16* W3b    = (__bf16*)(base + 5767168u);         // 5.5 MB, 128 KB
  __bf16* x2b    = (__bf16*)(base + (6u << 20));       // 6 MB, 4 MB  [gemm2 -> gemm3]
  __bf16* x1b    = (__bf16*)(base + (10u << 20));      // 10 MB, 6 MB [gemm1 -> gemm2]
  float*  O_part = (float*)(base + (6u << 20));        // 6 MB, 16 MB [flash -> combine]
  // peak ws use: 22 MB

  cvt_kernel<<<384, 256, 0, stream>>>(W1, W1b, 786432);
  cvt_kernel<<<192, 256, 0, stream>>>(W2, W2b, 393216);
  cvt_kernel<<<32,  256, 0, stream>>>(W3, W3b, 65536);
  pool_kernel<<<4096, 64, 0, stream>>>(ent_embs, ent_list, user_n);
  transpose_kernel<<<dim3(64, 2), 256, 0, stream>>>(user_n, user_t);
  gemm_bt<float,  4, 1><<<dim3(6, 32), 256, 0, stream>>>(ctx, W1b, x1b, 4096, 768, 1024);
  gemm_bt<__bf16, 4, 1><<<dim3(4, 32), 256, 0, stream>>>(x1b, W2b, x2b, 4096, 512, 768);
  gemm_bt<__bf16, 2, 0><<<dim3(1, 64), 256, 0, stream>>>(x2b, W3b, qb, 4096, 128, 512);
  flash_attn<<<dim3(64, 8), 256, 0, stream>>>(qb, user_n, user_t, O_part, l_part);
  combine_kernel<<<2048, 256, 0, stream>>>(O_part, l_part, out);
}

// Round 3
// 209.922 us; speedup vs baseline: 1.0333x; 1.0208x over previous
//
#include <hip/hip_runtime.h>
#include <hip/hip_bf16.h>

#define SENTINEL 24635

using bf16x8  = __attribute__((ext_vector_type(8))) __bf16;
using bf16x2  = __attribute__((ext_vector_type(2))) __bf16;
using floatx4 = __attribute__((ext_vector_type(4))) float;

__device__ inline bf16x8 cvt8(float4 a, float4 b) {
  bf16x8 v;
  v[0] = (__bf16)a.x; v[1] = (__bf16)a.y; v[2] = (__bf16)a.z; v[3] = (__bf16)a.w;
  v[4] = (__bf16)b.x; v[5] = (__bf16)b.y; v[6] = (__bf16)b.z; v[7] = (__bf16)b.w;
  return v;
}

// async global->LDS, 16 B per lane. LDS dest is wave-uniform base + lane*16.
__device__ inline void gll16(const __bf16* g, __bf16* l) {
  __builtin_amdgcn_global_load_lds(
      (const __attribute__((address_space(1))) unsigned int*)g,
      (__attribute__((address_space(3))) unsigned int*)l, 16, 0, 0);
}

// ---------------------------------------------------------------------------
// f32 -> bf16 elementwise convert, 8 elements/thread.
// ---------------------------------------------------------------------------
__global__ void cvt_kernel(const float* __restrict__ in, __bf16* __restrict__ out,
                           int n) {
  int i = (blockIdx.x * 256 + threadIdx.x) * 8;
  if (i < n) {
    float4 a = *(const float4*)(in + i);
    float4 b = *(const float4*)(in + i + 4);
    *(bf16x8*)(out + i) = cvt8(a, b);
  }
}

// ---------------------------------------------------------------------------
// Pool: user_n[b] = bf16( masked mean of ent_embs[ent_list[b,:cnt]] ).
// 4 rows per block (wave per row); cnt via ballot; gather loads independent.
// ---------------------------------------------------------------------------
__global__ __launch_bounds__(256) void pool_kernel(const float* __restrict__ ent,
                                                   const int* __restrict__ ent_list,
                                                   __bf16* __restrict__ user_n) {
  const int b = blockIdx.x * 4 + (threadIdx.x >> 6);
  const int lane = threadIdx.x & 63;
  int myidx = (lane < 50) ? ent_list[b * 50 + lane] : 0;
  unsigned long long m = __ballot(lane < 50 && myidx == SENTINEL);
  const int cnt = (m == 0) ? 50 : (int)__builtin_ctzll(m);

  float sx = 0.f, sy = 0.f;
  for (int l = 0; l < cnt; ++l) {
    int idx = __shfl(myidx, l);
    float2 e = *(const float2*)(ent + (size_t)idx * 128 + lane * 2);
    sx += e.x; sy += e.y;
  }
  float vx, vy;
  if (cnt == 0) {
    float2 e = *(const float2*)(ent + (size_t)SENTINEL * 128 + lane * 2);
    vx = e.x; vy = e.y;
  } else {
    float inv = 1.f / (float)cnt;
    vx = sx * inv; vy = sy * inv;
  }
  bf16x2 o; o[0] = (__bf16)vx; o[1] = (__bf16)vy;
  *(bf16x2*)(user_n + (size_t)b * 128 + lane * 2) = o;
}

// ---------------------------------------------------------------------------
// Transpose user_n [4096][128] bf16 -> user_t [128][4096] bf16 via LDS tiles.
// ---------------------------------------------------------------------------
__global__ __launch_bounds__(256) void transpose_kernel(const __bf16* __restrict__ in,
                                                        __bf16* __restrict__ out) {
  __shared__ __bf16 T[64][72];
  const int r0 = blockIdx.x * 64;
  const int c0 = blockIdx.y * 64;
  const int tid = threadIdx.x;
#pragma unroll
  for (int p = 0; p < 2; ++p) {
    int r = (tid >> 3) + p * 32;
    int c = (tid & 7) * 8;
    *(bf16x8*)&T[r][c] = *(const bf16x8*)(in + (size_t)(r0 + r) * 128 + c0 + c);
  }
  __syncthreads();
#pragma unroll
  for (int p = 0; p < 2; ++p) {
    int c = (tid >> 3) + p * 32;
    int r = (tid & 7) * 8;
    bf16x8 v;
#pragma unroll
    for (int j = 0; j < 8; ++j) v[j] = T[r + j][c];
    *(bf16x8*)(out + (size_t)(c0 + c) * 4096 + r0 + r) = v;
  }
}

// ---------------------------------------------------------------------------
// Split-K GEMM partials: P[z][m][n] = sum_{k in split z} A[m][k]*W[n][k]
// A,W bf16 row-major (K contiguous). Tile BM x 128, BK=32, 256 threads, 4
// waves 2x2; m97-style: global_load_lds width-16 staging into UNPADDED LDS
// ([row][32] bf16, 64 B rows), ds_read_b128 fragments, 16x16x32 bf16 MFMA.
// grid (N/128, M/BM, S); kPerSplit = K/S (multiple of 32).
// ---------------------------------------------------------------------------
template <int MT>
__global__ __launch_bounds__(256) void gemm_ks(const __bf16* __restrict__ A,
                                               const __bf16* __restrict__ W,
                                               float* __restrict__ P,
                                               int M, int N, int K, int kPerSplit) {
  constexpr int BM = MT * 32;
  __shared__ __bf16 As[BM][32];
  __shared__ __bf16 Bs[128][32];
  const int bn0 = blockIdx.x * 128;
  const int bm0 = blockIdx.y * BM;
  const int z   = blockIdx.z;
  const int tid  = threadIdx.x;
  const int w    = tid >> 6;
  const int lane = tid & 63;
  const int quad = lane >> 4;
  const int l16  = lane & 15;
  const int wr   = w >> 1;
  const int wc   = w & 1;
  const int lrow = lane >> 2;        // 0..15 row within 1 KB chunk
  const int lcol = (lane & 3) * 8;   // bf16 col within row

  floatx4 acc[MT][4];
#pragma unroll
  for (int mt = 0; mt < MT; ++mt)
#pragma unroll
    for (int nt = 0; nt < 4; ++nt) acc[mt][nt] = (floatx4){0.f, 0.f, 0.f, 0.f};

  const int kbeg = z * kPerSplit;
  const int kend = kbeg + kPerSplit;
  for (int k0 = kbeg; k0 < kend; k0 += 32) {
    __syncthreads();
    // A: BM/16 chunks of 1 KB (16 rows x 64 B); wave w stages BM/64 of them.
#pragma unroll
    for (int p = 0; p < BM / 64; ++p) {
      int c = w * (BM / 64) + p;
      gll16(A + (size_t)(bm0 + c * 16 + lrow) * K + k0 + lcol, &As[c * 16][0]);
    }
    // B: 8 chunks; wave w stages 2.
#pragma unroll
    for (int p = 0; p < 2; ++p) {
      int c = w * 2 + p;
      gll16(W + (size_t)(bn0 + c * 16 + lrow) * K + k0 + lcol, &Bs[c * 16][0]);
    }
    __syncthreads();
    bf16x8 af[MT], bfr[4];
#pragma unroll
    for (int mt = 0; mt < MT; ++mt)
      af[mt] = *(const bf16x8*)&As[wr * (MT * 16) + mt * 16 + l16][quad * 8];
#pragma unroll
    for (int nt = 0; nt < 4; ++nt)
      bfr[nt] = *(const bf16x8*)&Bs[wc * 64 + nt * 16 + l16][quad * 8];
#pragma unroll
    for (int mt = 0; mt < MT; ++mt)
#pragma unroll
      for (int nt = 0; nt < 4; ++nt)
        acc[mt][nt] =
            __builtin_amdgcn_mfma_f32_16x16x32_bf16(af[mt], bfr[nt], acc[mt][nt], 0, 0, 0);
  }

  float* Pz = P + (size_t)z * M * N;
#pragma unroll
  for (int mt = 0; mt < MT; ++mt) {
    const int row0 = bm0 + wr * (MT * 16) + mt * 16 + quad * 4;
#pragma unroll
    for (int nt = 0; nt < 4; ++nt) {
      const int col = bn0 + wc * 64 + nt * 16 + l16;
#pragma unroll
      for (int r = 0; r < 4; ++r) {
        Pz[(size_t)(row0 + r) * N + col] = acc[mt][nt][r];
      }
    }
  }
}

// ---------------------------------------------------------------------------
// Reduce split-K partials: out = bf16( act( sum_z P[z] ) ), 8 elems/thread.
// ---------------------------------------------------------------------------
template <int S, int RELU>
__global__ void reduce_ks(const float* __restrict__ P, __bf16* __restrict__ out,
                          int n) {
  int i = (blockIdx.x * 256 + threadIdx.x) * 8;
  float4 s0 = {0.f, 0.f, 0.f, 0.f}, s1 = {0.f, 0.f, 0.f, 0.f};
#pragma unroll
  for (int s = 0; s < S; ++s) {
    float4 a = *(const float4*)(P + (size_t)s * n + i);
    float4 b = *(const float4*)(P + (size_t)s * n + i + 4);
    s0.x += a.x; s0.y += a.y; s0.z += a.z; s0.w += a.w;
    s1.x += b.x; s1.y += b.y; s1.z += b.z; s1.w += b.w;
  }
  if (RELU) {
    s0.x = fmaxf(s0.x, 0.f); s0.y = fmaxf(s0.y, 0.f);
    s0.z = fmaxf(s0.z, 0.f); s0.w = fmaxf(s0.w, 0.f);
    s1.x = fmaxf(s1.x, 0.f); s1.y = fmaxf(s1.y, 0.f);
    s1.z = fmaxf(s1.z, 0.f); s1.w = fmaxf(s1.w, 0.f);
  }
  *(bf16x8*)(out + i) = cvt8(s0, s1);
}

// ---------------------------------------------------------------------------
// Flash attention, no max-subtraction (|scores| ~ 1e-2: exp is safe):
//   O_part[split] = sum_chunks exp(Q Uc^T * scale) @ Uc ; l_part = row sums.
// grid (64 q-tiles, 8 key-splits) = 512 blocks, 256 threads.
// ---------------------------------------------------------------------------
__global__ __launch_bounds__(256) void flash_attn(const __bf16* __restrict__ Q,
                                                  const __bf16* __restrict__ Un_g,
                                                  const __bf16* __restrict__ Ut_g,
                                                  float* __restrict__ O_part,
                                                  float* __restrict__ l_part) {
  __shared__ __bf16 Un[64][136];
  __shared__ __bf16 Ut[128][72];
  __shared__ __bf16 Ps[4][16][72];
  const int tid  = threadIdx.x;
  const int w    = tid >> 6;
  const int lane = tid & 63;
  const int quad = lane >> 4;
  const int l16  = lane & 15;
  const int qrow0 = blockIdx.x * 64;
  const int split = blockIdx.y;
  const float scale = 0.08838834764831845f;  // 1/sqrt(128)

  bf16x8 aq[4];
#pragma unroll
  for (int c = 0; c < 4; ++c)
    aq[c] = *(const bf16x8*)(Q + (size_t)(qrow0 + w * 16 + l16) * 128 + c * 32 + quad * 8);

  floatx4 o[8];
#pragma unroll
  for (int t = 0; t < 8; ++t) o[t] = (floatx4){0.f, 0.f, 0.f, 0.f};
  float lsum[4] = {0.f, 0.f, 0.f, 0.f};

  for (int chunk = 0; chunk < 8; ++chunk) {
    const int key0 = split * 512 + chunk * 64;
    __syncthreads();
#pragma unroll
    for (int p = 0; p < 4; ++p) {
      int r = (tid >> 4) + p * 16;
      int c = (tid & 15) * 8;
      *(bf16x8*)&Un[r][c] = *(const bf16x8*)(Un_g + (size_t)(key0 + r) * 128 + c);
    }
#pragma unroll
    for (int p = 0; p < 4; ++p) {
      int d = (tid >> 3) + p * 32;
      int kk = (tid & 7) * 8;
      *(bf16x8*)&Ut[d][kk] = *(const bf16x8*)(Ut_g + (size_t)d * 4096 + key0 + kk);
    }
    __syncthreads();

#pragma unroll
    for (int t = 0; t < 4; ++t) {
      floatx4 s = (floatx4){0.f, 0.f, 0.f, 0.f};
#pragma unroll
      for (int c = 0; c < 4; ++c) {
        bf16x8 bk = *(const bf16x8*)&Un[t * 16 + l16][c * 32 + quad * 8];
        s = __builtin_amdgcn_mfma_f32_16x16x32_bf16(aq[c], bk, s, 0, 0, 0);
      }
#pragma unroll
      for (int r = 0; r < 4; ++r) {
        float pv = __expf(s[r] * scale);
        lsum[r] += pv;
        Ps[w][quad * 4 + r][t * 16 + l16] = (__bf16)pv;
      }
    }
    __syncthreads();

#pragma unroll
    for (int c = 0; c < 2; ++c) {
      bf16x8 ap = *(const bf16x8*)&Ps[w][l16][c * 32 + quad * 8];
#pragma unroll
      for (int dt = 0; dt < 8; ++dt) {
        bf16x8 bv = *(const bf16x8*)&Ut[dt * 16 + l16][c * 32 + quad * 8];
        o[dt] = __builtin_amdgcn_mfma_f32_16x16x32_bf16(ap, bv, o[dt], 0, 0, 0);
      }
    }
  }

#pragma unroll
  for (int r = 0; r < 4; ++r) {
    float v = lsum[r];
    v += __shfl_xor(v, 1);
    v += __shfl_xor(v, 2);
    v += __shfl_xor(v, 4);
    v += __shfl_xor(v, 8);
    lsum[r] = v;
  }

  const int row0 = qrow0 + w * 16 + quad * 4;
  float* Ob = O_part + (size_t)split * 4096 * 128;
#pragma unroll
  for (int dt = 0; dt < 8; ++dt) {
#pragma unroll
    for (int r = 0; r < 4; ++r) {
      Ob[(size_t)(row0 + r) * 128 + dt * 16 + l16] = o[dt][r];
    }
  }
  if (l16 == 0) {
#pragma unroll
    for (int r = 0; r < 4; ++r) l_part[split * 4096 + row0 + r] = lsum[r];
  }
}

// ---------------------------------------------------------------------------
// Combine 8 key-splits: out = (sum_s O_s) / (sum_s l_s)
// ---------------------------------------------------------------------------
__global__ void combine_kernel(const float* __restrict__ O_part,
                               const float* __restrict__ l_part,
                               float* __restrict__ out) {
  const int i = blockIdx.x * 256 + threadIdx.x;
  const int row = i >> 7;
  float num = 0.f, den = 0.f;
#pragma unroll
  for (int s = 0; s < 8; ++s) {
    num += O_part[(size_t)s * 524288 + i];
    den += l_part[s * 4096 + row];
  }
  out[i] = num / den;
}

extern "C" void kernel_launch(void* const* d_in, const int* in_sizes, int n_in,
                              void* d_out, int out_size, void* d_ws, size_t ws_size,
                              hipStream_t stream) {
  (void)in_sizes; (void)n_in; (void)out_size; (void)ws_size;
  const float* ctx      = (const float*)d_in[0];  // [4096,1024]
  const float* ent_embs = (const float*)d_in[1];  // [24636,128]
  const float* W1       = (const float*)d_in[2];  // [768,1024]
  const float* W2       = (const float*)d_in[3];  // [512,768]
  const float* W3       = (const float*)d_in[4];  // [128,512]
  const int*   ent_list = (const int*)d_in[5];    // [4096,50]
  float* out = (float*)d_out;

  // ws layout (1 MB units unless noted); peak use 96 MB (ws is 256 MB).
  char* base = (char*)d_ws;
  __bf16* user_n = (__bf16*)(base);                       // 1 MB
  __bf16* user_t = (__bf16*)(base + (1ull << 20));        // 1 MB
  __bf16* qb     = (__bf16*)(base + (2ull << 20));        // 1 MB
  float*  l_part = (float*)(base + (3ull << 20));         // 128 KB
  __bf16* ctxb   = (__bf16*)(base + (4ull << 20));        // 8 MB
  __bf16* W1b    = (__bf16*)(base + (12ull << 20));       // 1.5 MB
  __bf16* W2b    = (__bf16*)(base + 14155776ull);         // 13.5 MB, 0.75 MB
  __bf16* W3b    = (__bf16*)(base + 14942208ull);         // 14.25 MB, 128 KB
  __bf16* x1b    = (__bf16*)(base + (15ull << 20));       // 6 MB
  __bf16* x2b    = (__bf16*)(base + (21ull << 20));       // 4 MB
  float*  O_part = (float*)(base + (25ull << 20));        // 16 MB
  float*  Pp     = (float*)(base + (48ull << 20));        // up to 48 MB (split-K partials)

  cvt_kernel<<<2048, 256, 0, stream>>>(ctx, ctxb, 4194304);
  cvt_kernel<<<384, 256, 0, stream>>>(W1, W1b, 786432);
  cvt_kernel<<<192, 256, 0, stream>>>(W2, W2b, 393216);
  cvt_kernel<<<32,  256, 0, stream>>>(W3, W3b, 65536);
  pool_kernel<<<1024, 256, 0, stream>>>(ent_embs, ent_list, user_n);
  transpose_kernel<<<dim3(64, 2), 256, 0, stream>>>(user_n, user_t);

  // MLP: split-K partials (fp32) + reduce(relu/cvt).
  gemm_ks<4><<<dim3(6, 32, 4), 256, 0, stream>>>(ctxb, W1b, Pp, 4096, 768, 1024, 256);
  reduce_ks<4, 1><<<1536, 256, 0, stream>>>(Pp, x1b, 3145728);
  gemm_ks<4><<<dim3(4, 32, 4), 256, 0, stream>>>(x1b, W2b, Pp, 4096, 512, 768, 192);
  reduce_ks<4, 1><<<1024, 256, 0, stream>>>(Pp, x2b, 2097152);
  gemm_ks<2><<<dim3(1, 64, 8), 256, 0, stream>>>(x2b, W3b, Pp, 4096, 128, 512, 64);
  reduce_ks<8, 0><<<256, 256, 0, stream>>>(Pp, qb, 524288);

  flash_attn<<<dim3(64, 8), 256, 0, stream>>>(qb, user_n, user_t, O_part, l_part);
  combine_kernel<<<2048, 256, 0, stream>>>(O_part, l_part, out);
}

// Round 4
// 176.971 us; speedup vs baseline: 1.2257x; 1.1862x over previous
//
#include <hip/hip_runtime.h>
#include <hip/hip_bf16.h>

#define SENTINEL 24635

using bf16x8  = __attribute__((ext_vector_type(8))) __bf16;
using bf16x2  = __attribute__((ext_vector_type(2))) __bf16;
using floatx4 = __attribute__((ext_vector_type(4))) float;

__device__ inline bf16x8 cvt8(float4 a, float4 b) {
  bf16x8 v;
  v[0] = (__bf16)a.x; v[1] = (__bf16)a.y; v[2] = (__bf16)a.z; v[3] = (__bf16)a.w;
  v[4] = (__bf16)b.x; v[5] = (__bf16)b.y; v[6] = (__bf16)b.z; v[7] = (__bf16)b.w;
  return v;
}

// async global->LDS, 16 B per lane. LDS dest = wave-uniform base + lane*16.
__device__ inline void gll16(const __bf16* g, __bf16* l) {
  __builtin_amdgcn_global_load_lds(
      (const __attribute__((address_space(1))) unsigned int*)g,
      (__attribute__((address_space(3))) unsigned int*)l, 16, 0, 0);
}

// ---------------------------------------------------------------------------
// One-shot f32 -> bf16 convert of ctx + W1 + W2 + W3 (segment dispatch),
// 8 elements/thread.
// ---------------------------------------------------------------------------
__global__ void cvt_all_kernel(const float* __restrict__ s0, __bf16* __restrict__ d0,
                               const float* __restrict__ s1, __bf16* __restrict__ d1,
                               const float* __restrict__ s2, __bf16* __restrict__ d2,
                               const float* __restrict__ s3, __bf16* __restrict__ d3) {
  // sizes in 8-elem units: ctx 524288, W1 98304, W2 49152, W3 8192
  int g = blockIdx.x * 256 + threadIdx.x;
  const float* s; __bf16* d; int i;
  if (g < 524288)                 { s = s0; d = d0; i = g; }
  else if (g < 524288 + 98304)    { s = s1; d = d1; i = g - 524288; }
  else if (g < 524288 + 147456)   { s = s2; d = d2; i = g - 622592; }
  else if (g < 524288 + 155648)   { s = s3; d = d3; i = g - 671744; }
  else return;
  i *= 8;
  float4 a = *(const float4*)(s + i);
  float4 b = *(const float4*)(s + i + 4);
  *(bf16x8*)(d + i) = cvt8(a, b);
}

// ---------------------------------------------------------------------------
// Pool: user_n[b] = bf16( masked mean of ent_embs[ent_list[b,:cnt]] ).
// 4 rows per block (wave per row); cnt via ballot; gather loads independent.
// ---------------------------------------------------------------------------
__global__ __launch_bounds__(256) void pool_kernel(const float* __restrict__ ent,
                                                   const int* __restrict__ ent_list,
                                                   __bf16* __restrict__ user_n) {
  const int b = blockIdx.x * 4 + (threadIdx.x >> 6);
  const int lane = threadIdx.x & 63;
  int myidx = (lane < 50) ? ent_list[b * 50 + lane] : 0;
  unsigned long long m = __ballot(lane < 50 && myidx == SENTINEL);
  const int cnt = (m == 0) ? 50 : (int)__builtin_ctzll(m);

  float sx = 0.f, sy = 0.f;
  for (int l = 0; l < cnt; ++l) {
    int idx = __shfl(myidx, l);
    float2 e = *(const float2*)(ent + (size_t)idx * 128 + lane * 2);
    sx += e.x; sy += e.y;
  }
  float vx, vy;
  if (cnt == 0) {
    float2 e = *(const float2*)(ent + (size_t)SENTINEL * 128 + lane * 2);
    vx = e.x; vy = e.y;
  } else {
    float inv = 1.f / (float)cnt;
    vx = sx * inv; vy = sy * inv;
  }
  bf16x2 o; o[0] = (__bf16)vx; o[1] = (__bf16)vy;
  *(bf16x2*)(user_n + (size_t)b * 128 + lane * 2) = o;
}

// ---------------------------------------------------------------------------
// Transpose user_n [4096][128] bf16 -> user_t [128][4096] bf16 via LDS tiles.
// ---------------------------------------------------------------------------
__global__ __launch_bounds__(256) void transpose_kernel(const __bf16* __restrict__ in,
                                                        __bf16* __restrict__ out) {
  __shared__ __bf16 T[64][72];
  const int r0 = blockIdx.x * 64;
  const int c0 = blockIdx.y * 64;
  const int tid = threadIdx.x;
#pragma unroll
  for (int p = 0; p < 2; ++p) {
    int r = (tid >> 3) + p * 32;
    int c = (tid & 7) * 8;
    *(bf16x8*)&T[r][c] = *(const bf16x8*)(in + (size_t)(r0 + r) * 128 + c0 + c);
  }
  __syncthreads();
#pragma unroll
  for (int p = 0; p < 2; ++p) {
    int c = (tid >> 3) + p * 32;
    int r = (tid & 7) * 8;
    bf16x8 v;
#pragma unroll
    for (int j = 0; j < 8; ++j) v[j] = T[r + j][c];
    *(bf16x8*)(out + (size_t)(c0 + c) * 4096 + r0 + r) = v;
  }
}

// ---------------------------------------------------------------------------
// Single-pass GEMM: C[m][n] = bf16( act( sum_k A[m][k]*W[n][k] ) )
// A,W,C bf16 row-major (K contiguous). Tile (MT*32) x (NT*32), BK=64,
// 256 threads, 4 waves 2x2: wave (wr,wc) covers rows wr*MT*16+, cols wc*NT*16+.
// m97-style staging: global_load_lds width-16 into UNPADDED LDS rows of 64
// bf16 (128 B); each 1 KB chunk = 8 rows, lane -> (row=lane>>3, col=(lane&7)*8).
// Requires M%(MT*32)==0, N%(NT*32)==0, K%64==0.
// ---------------------------------------------------------------------------
template <int MT, int NT, int RELU>
__global__ __launch_bounds__(256) void gemm_bt(const __bf16* __restrict__ A,
                                               const __bf16* __restrict__ W,
                                               __bf16* __restrict__ C,
                                               int M, int N, int K) {
  constexpr int BM = MT * 32;
  constexpr int BN = NT * 32;
  __shared__ __bf16 As[BM][64];
  __shared__ __bf16 Bs[BN][64];
  const int bn0 = blockIdx.x * BN;
  const int bm0 = blockIdx.y * BM;
  const int tid  = threadIdx.x;
  const int w    = tid >> 6;
  const int lane = tid & 63;
  const int quad = lane >> 4;
  const int l16  = lane & 15;
  const int wr   = w >> 1;
  const int wc   = w & 1;
  const int lrow = lane >> 3;        // 0..7 row within 1 KB chunk
  const int lcol = (lane & 7) * 8;   // bf16 col within row

  floatx4 acc[MT][NT];
#pragma unroll
  for (int mt = 0; mt < MT; ++mt)
#pragma unroll
    for (int nt = 0; nt < NT; ++nt) acc[mt][nt] = (floatx4){0.f, 0.f, 0.f, 0.f};

  for (int k0 = 0; k0 < K; k0 += 64) {
    __syncthreads();
#pragma unroll
    for (int c = w; c < BM / 8; c += 4)
      gll16(A + (size_t)(bm0 + c * 8 + lrow) * K + k0 + lcol, &As[c * 8][0]);
#pragma unroll
    for (int c = w; c < BN / 8; c += 4)
      gll16(W + (size_t)(bn0 + c * 8 + lrow) * K + k0 + lcol, &Bs[c * 8][0]);
    __syncthreads();
#pragma unroll
    for (int s = 0; s < 2; ++s) {
      bf16x8 af[MT], bfr[NT];
#pragma unroll
      for (int mt = 0; mt < MT; ++mt)
        af[mt] = *(const bf16x8*)&As[wr * (MT * 16) + mt * 16 + l16][s * 32 + quad * 8];
#pragma unroll
      for (int nt = 0; nt < NT; ++nt)
        bfr[nt] = *(const bf16x8*)&Bs[wc * (NT * 16) + nt * 16 + l16][s * 32 + quad * 8];
#pragma unroll
      for (int mt = 0; mt < MT; ++mt)
#pragma unroll
        for (int nt = 0; nt < NT; ++nt)
          acc[mt][nt] =
              __builtin_amdgcn_mfma_f32_16x16x32_bf16(af[mt], bfr[nt], acc[mt][nt], 0, 0, 0);
    }
  }

#pragma unroll
  for (int mt = 0; mt < MT; ++mt) {
    const int row0 = bm0 + wr * (MT * 16) + mt * 16 + quad * 4;
#pragma unroll
    for (int nt = 0; nt < NT; ++nt) {
      const int col = bn0 + wc * (NT * 16) + nt * 16 + l16;
#pragma unroll
      for (int r = 0; r < 4; ++r) {
        float v = acc[mt][nt][r];
        if (RELU) v = fmaxf(v, 0.f);
        C[(size_t)(row0 + r) * N + col] = (__bf16)v;
      }
    }
  }
}

// ---------------------------------------------------------------------------
// Flash attention, no max-subtraction (|scores| ~ 1e-2: exp is safe):
//   O_part[split] = sum_chunks exp(Q Uc^T * scale) @ Uc ; l_part = row sums.
// grid (64 q-tiles, 12 key-splits) = 768 blocks (3/CU), 256 threads.
// Splits cover 64 chunks of 64 keys: first 4 splits get 6 chunks, rest 5.
// ---------------------------------------------------------------------------
__global__ __launch_bounds__(256) void flash_attn(const __bf16* __restrict__ Q,
                                                  const __bf16* __restrict__ Un_g,
                                                  const __bf16* __restrict__ Ut_g,
                                                  float* __restrict__ O_part,
                                                  float* __restrict__ l_part) {
  __shared__ __bf16 Un[64][136];
  __shared__ __bf16 Ut[128][72];
  __shared__ __bf16 Ps[4][16][72];
  const int tid  = threadIdx.x;
  const int w    = tid >> 6;
  const int lane = tid & 63;
  const int quad = lane >> 4;
  const int l16  = lane & 15;
  const int qrow0 = blockIdx.x * 64;
  const int split = blockIdx.y;
  const int ch0 = split * 5 + min(split, 4);
  const int nch = 5 + (split < 4 ? 1 : 0);
  const float scale = 0.08838834764831845f;  // 1/sqrt(128)

  bf16x8 aq[4];
#pragma unroll
  for (int c = 0; c < 4; ++c)
    aq[c] = *(const bf16x8*)(Q + (size_t)(qrow0 + w * 16 + l16) * 128 + c * 32 + quad * 8);

  floatx4 o[8];
#pragma unroll
  for (int t = 0; t < 8; ++t) o[t] = (floatx4){0.f, 0.f, 0.f, 0.f};
  float lsum[4] = {0.f, 0.f, 0.f, 0.f};

  for (int chunk = 0; chunk < nch; ++chunk) {
    const int key0 = (ch0 + chunk) * 64;
    __syncthreads();
#pragma unroll
    for (int p = 0; p < 4; ++p) {
      int r = (tid >> 4) + p * 16;
      int c = (tid & 15) * 8;
      *(bf16x8*)&Un[r][c] = *(const bf16x8*)(Un_g + (size_t)(key0 + r) * 128 + c);
    }
#pragma unroll
    for (int p = 0; p < 4; ++p) {
      int d = (tid >> 3) + p * 32;
      int kk = (tid & 7) * 8;
      *(bf16x8*)&Ut[d][kk] = *(const bf16x8*)(Ut_g + (size_t)d * 4096 + key0 + kk);
    }
    __syncthreads();

#pragma unroll
    for (int t = 0; t < 4; ++t) {
      floatx4 s = (floatx4){0.f, 0.f, 0.f, 0.f};
#pragma unroll
      for (int c = 0; c < 4; ++c) {
        bf16x8 bk = *(const bf16x8*)&Un[t * 16 + l16][c * 32 + quad * 8];
        s = __builtin_amdgcn_mfma_f32_16x16x32_bf16(aq[c], bk, s, 0, 0, 0);
      }
#pragma unroll
      for (int r = 0; r < 4; ++r) {
        float pv = __expf(s[r] * scale);
        lsum[r] += pv;
        Ps[w][quad * 4 + r][t * 16 + l16] = (__bf16)pv;
      }
    }
    __syncthreads();

#pragma unroll
    for (int c = 0; c < 2; ++c) {
      bf16x8 ap = *(const bf16x8*)&Ps[w][l16][c * 32 + quad * 8];
#pragma unroll
      for (int dt = 0; dt < 8; ++dt) {
        bf16x8 bv = *(const bf16x8*)&Ut[dt * 16 + l16][c * 32 + quad * 8];
        o[dt] = __builtin_amdgcn_mfma_f32_16x16x32_bf16(ap, bv, o[dt], 0, 0, 0);
      }
    }
  }

#pragma unroll
  for (int r = 0; r < 4; ++r) {
    float v = lsum[r];
    v += __shfl_xor(v, 1);
    v += __shfl_xor(v, 2);
    v += __shfl_xor(v, 4);
    v += __shfl_xor(v, 8);
    lsum[r] = v;
  }

  const int row0 = qrow0 + w * 16 + quad * 4;
  float* Ob = O_part + (size_t)split * 4096 * 128;
#pragma unroll
  for (int dt = 0; dt < 8; ++dt) {
#pragma unroll
    for (int r = 0; r < 4; ++r) {
      Ob[(size_t)(row0 + r) * 128 + dt * 16 + l16] = o[dt][r];
    }
  }
  if (l16 == 0) {
#pragma unroll
    for (int r = 0; r < 4; ++r) l_part[split * 4096 + row0 + r] = lsum[r];
  }
}

// ---------------------------------------------------------------------------
// Combine 12 key-splits: out = (sum_s O_s) / (sum_s l_s)
// ---------------------------------------------------------------------------
__global__ void combine_kernel(const float* __restrict__ O_part,
                               const float* __restrict__ l_part,
                               float* __restrict__ out) {
  const int i = blockIdx.x * 256 + threadIdx.x;
  const int row = i >> 7;
  float num = 0.f, den = 0.f;
#pragma unroll
  for (int s = 0; s < 12; ++s) {
    num += O_part[(size_t)s * 524288 + i];
    den += l_part[s * 4096 + row];
  }
  out[i] = num / den;
}

extern "C" void kernel_launch(void* const* d_in, const int* in_sizes, int n_in,
                              void* d_out, int out_size, void* d_ws, size_t ws_size,
                              hipStream_t stream) {
  (void)in_sizes; (void)n_in; (void)out_size; (void)ws_size;
  const float* ctx      = (const float*)d_in[0];  // [4096,1024]
  const float* ent_embs = (const float*)d_in[1];  // [24636,128]
  const float* W1       = (const float*)d_in[2];  // [768,1024]
  const float* W2       = (const float*)d_in[3];  // [512,768]
  const float* W3       = (const float*)d_in[4];  // [128,512]
  const int*   ent_list = (const int*)d_in[5];    // [4096,50]
  float* out = (float*)d_out;

  // ws layout; peak use 49 MB.
  char* base = (char*)d_ws;
  __bf16* user_n = (__bf16*)(base);                       // 1 MB
  __bf16* user_t = (__bf16*)(base + (1ull << 20));        // 1 MB
  __bf16* qb     = (__bf16*)(base + (2ull << 20));        // 1 MB
  float*  l_part = (float*)(base + (3ull << 20));         // 192 KB
  __bf16* ctxb   = (__bf16*)(base + (4ull << 20));        // 8 MB
  __bf16* W1b    = (__bf16*)(base + (12ull << 20));       // 1.5 MB
  __bf16* W2b    = (__bf16*)(base + 14155776ull);         // 13.5 MB, 0.75 MB
  __bf16* W3b    = (__bf16*)(base + 14942208ull);         // 14.25 MB, 128 KB
  __bf16* x1b    = (__bf16*)(base + (15ull << 20));       // 6 MB
  __bf16* x2b    = (__bf16*)(base + (21ull << 20));       // 4 MB
  float*  O_part = (float*)(base + (25ull << 20));        // 24 MB

  cvt_all_kernel<<<2656, 256, 0, stream>>>(ctx, ctxb, W1, W1b, W2, W2b, W3, W3b);
  pool_kernel<<<1024, 256, 0, stream>>>(ent_embs, ent_list, user_n);
  transpose_kernel<<<dim3(64, 2), 256, 0, stream>>>(user_n, user_t);

  // MLP: single-pass 64x64 (gemm3: 32x64) tiles, relu+cvt fused in epilogue.
  gemm_bt<2, 2, 1><<<dim3(12, 64), 256, 0, stream>>>(ctxb, W1b, x1b, 4096, 768, 1024);
  gemm_bt<2, 2, 1><<<dim3(8, 64), 256, 0, stream>>>(x1b, W2b, x2b, 4096, 512, 768);
  gemm_bt<1, 2, 0><<<dim3(2, 128), 256, 0, stream>>>(x2b, W3b, qb, 4096, 128, 512);

  flash_attn<<<dim3(64, 12), 256, 0, stream>>>(qb, user_n, user_t, O_part, l_part);
  combine_kernel<<<2048, 256, 0, stream>>>(O_part, l_part, out);
}

// Round 5
// 169.567 us; speedup vs baseline: 1.2792x; 1.0437x over previous
//
#include <hip/hip_runtime.h>
#include <hip/hip_bf16.h>

#define SENTINEL 24635

using bf16x8  = __attribute__((ext_vector_type(8))) __bf16;
using bf16x2  = __attribute__((ext_vector_type(2))) __bf16;
using floatx4 = __attribute__((ext_vector_type(4))) float;

__device__ inline bf16x8 cvt8(float4 a, float4 b) {
  bf16x8 v;
  v[0] = (__bf16)a.x; v[1] = (__bf16)a.y; v[2] = (__bf16)a.z; v[3] = (__bf16)a.w;
  v[4] = (__bf16)b.x; v[5] = (__bf16)b.y; v[6] = (__bf16)b.z; v[7] = (__bf16)b.w;
  return v;
}

// async global->LDS, 16 B per lane. LDS dest = wave-uniform base + lane*16.
__device__ inline void gll16(const __bf16* g, __bf16* l) {
  __builtin_amdgcn_global_load_lds(
      (const __attribute__((address_space(1))) unsigned int*)g,
      (__attribute__((address_space(3))) unsigned int*)l, 16, 0, 0);
}

// ---------------------------------------------------------------------------
// One-shot f32 -> bf16 convert of ctx + W1 + W2 + W3, 8 elements/thread.
// ---------------------------------------------------------------------------
__global__ void cvt_all_kernel(const float* __restrict__ s0, __bf16* __restrict__ d0,
                               const float* __restrict__ s1, __bf16* __restrict__ d1,
                               const float* __restrict__ s2, __bf16* __restrict__ d2,
                               const float* __restrict__ s3, __bf16* __restrict__ d3) {
  // sizes in 8-elem units: ctx 524288, W1 98304, W2 49152, W3 8192
  int g = blockIdx.x * 256 + threadIdx.x;
  const float* s; __bf16* d; int i;
  if (g < 524288)                 { s = s0; d = d0; i = g; }
  else if (g < 524288 + 98304)    { s = s1; d = d1; i = g - 524288; }
  else if (g < 524288 + 147456)   { s = s2; d = d2; i = g - 622592; }
  else if (g < 524288 + 155648)   { s = s3; d = d3; i = g - 671744; }
  else return;
  i *= 8;
  float4 a = *(const float4*)(s + i);
  float4 b = *(const float4*)(s + i + 4);
  *(bf16x8*)(d + i) = cvt8(a, b);
}

// ---------------------------------------------------------------------------
// Pool: user_n[b] = bf16( masked mean of ent_embs[ent_list[b,:cnt]] ).
// 4 rows/block (wave per row). Gather in batches of 10 independent loads
// (latency overlap); mask-accumulate; wave-uniform early break per batch.
// ---------------------------------------------------------------------------
__global__ __launch_bounds__(256) void pool_kernel(const float* __restrict__ ent,
                                                   const int* __restrict__ ent_list,
                                                   __bf16* __restrict__ user_n) {
  const int b = blockIdx.x * 4 + (threadIdx.x >> 6);
  const int lane = threadIdx.x & 63;
  int myidx = (lane < 50) ? ent_list[b * 50 + lane] : 0;
  unsigned long long m = __ballot(lane < 50 && myidx == SENTINEL);
  const int cnt = (m == 0) ? 50 : (int)__builtin_ctzll(m);

  float sx = 0.f, sy = 0.f;
  for (int l0 = 0; l0 < 50; l0 += 10) {
    if (l0 >= cnt) break;  // wave-uniform
    float2 e[10];
#pragma unroll
    for (int j = 0; j < 10; ++j) {
      int idx = __shfl(myidx, l0 + j);
      e[j] = *(const float2*)(ent + (size_t)idx * 128 + lane * 2);
    }
#pragma unroll
    for (int j = 0; j < 10; ++j) {
      if (l0 + j < cnt) { sx += e[j].x; sy += e[j].y; }
    }
  }
  float vx, vy;
  if (cnt == 0) {
    float2 e = *(const float2*)(ent + (size_t)SENTINEL * 128 + lane * 2);
    vx = e.x; vy = e.y;
  } else {
    float inv = 1.f / (float)cnt;
    vx = sx * inv; vy = sy * inv;
  }
  bf16x2 o; o[0] = (__bf16)vx; o[1] = (__bf16)vy;
  *(bf16x2*)(user_n + (size_t)b * 128 + lane * 2) = o;
}

// ---------------------------------------------------------------------------
// Transpose user_n [4096][128] bf16 -> user_t [128][4096] bf16 via LDS tiles.
// ---------------------------------------------------------------------------
__global__ __launch_bounds__(256) void transpose_kernel(const __bf16* __restrict__ in,
                                                        __bf16* __restrict__ out) {
  __shared__ __bf16 T[64][72];
  const int r0 = blockIdx.x * 64;
  const int c0 = blockIdx.y * 64;
  const int tid = threadIdx.x;
#pragma unroll
  for (int p = 0; p < 2; ++p) {
    int r = (tid >> 3) + p * 32;
    int c = (tid & 7) * 8;
    *(bf16x8*)&T[r][c] = *(const bf16x8*)(in + (size_t)(r0 + r) * 128 + c0 + c);
  }
  __syncthreads();
#pragma unroll
  for (int p = 0; p < 2; ++p) {
    int c = (tid >> 3) + p * 32;
    int r = (tid & 7) * 8;
    bf16x8 v;
#pragma unroll
    for (int j = 0; j < 8; ++j) v[j] = T[r + j][c];
    *(bf16x8*)(out + (size_t)(c0 + c) * 4096 + r0 + r) = v;
  }
}

// ---------------------------------------------------------------------------
// Single-pass GEMM: C[m][n] = bf16( act( sum_k A[m][k]*W[n][k] ) )
// A,W,C bf16 row-major (K contiguous). Block tile (WR*MT*16) x (WC*NT*16),
// BK=64, 256 threads = 4 waves arranged WR x WC.
// LDS: two K-slabs of 32 (m97 layout: unpadded 64 B rows, gll16 chunks of
// 16 rows); fragment reads hit m97's measured-OK bank pattern.
// Requires M%BM==0, N%BN==0, K%64==0.
// ---------------------------------------------------------------------------
template <int WR, int WC, int MT, int NT, int RELU>
__global__ __launch_bounds__(256) void gemm_bt(const __bf16* __restrict__ A,
                                               const __bf16* __restrict__ W,
                                               __bf16* __restrict__ C,
                                               int M, int N, int K) {
  constexpr int BM = WR * MT * 16;
  constexpr int BN = WC * NT * 16;
  __shared__ __bf16 As[2][BM][32];
  __shared__ __bf16 Bs[2][BN][32];
  const int bn0 = blockIdx.x * BN;
  const int bm0 = blockIdx.y * BM;
  const int tid  = threadIdx.x;
  const int w    = tid >> 6;
  const int lane = tid & 63;
  const int quad = lane >> 4;
  const int l16  = lane & 15;
  const int wr   = w / WC;
  const int wc   = w % WC;
  const int lrow = lane >> 2;        // 0..15 row within 1 KB chunk
  const int lcol = (lane & 3) * 8;   // bf16 col within 32-wide slab row

  floatx4 acc[MT][NT];
#pragma unroll
  for (int mt = 0; mt < MT; ++mt)
#pragma unroll
    for (int nt = 0; nt < NT; ++nt) acc[mt][nt] = (floatx4){0.f, 0.f, 0.f, 0.f};

  constexpr int nAc = 2 * (BM / 16);  // chunks: slab-major
  constexpr int nBc = 2 * (BN / 16);
  for (int k0 = 0; k0 < K; k0 += 64) {
    __syncthreads();
#pragma unroll
    for (int c = w; c < nAc; c += 4) {
      int s = c / (BM / 16);
      int r = (c % (BM / 16)) * 16;
      gll16(A + (size_t)(bm0 + r + lrow) * K + k0 + s * 32 + lcol, &As[s][r][0]);
    }
#pragma unroll
    for (int c = w; c < nBc; c += 4) {
      int s = c / (BN / 16);
      int r = (c % (BN / 16)) * 16;
      gll16(W + (size_t)(bn0 + r + lrow) * K + k0 + s * 32 + lcol, &Bs[s][r][0]);
    }
    __syncthreads();
#pragma unroll
    for (int s = 0; s < 2; ++s) {
      bf16x8 af[MT], bfr[NT];
#pragma unroll
      for (int mt = 0; mt < MT; ++mt)
        af[mt] = *(const bf16x8*)&As[s][wr * (MT * 16) + mt * 16 + l16][quad * 8];
#pragma unroll
      for (int nt = 0; nt < NT; ++nt)
        bfr[nt] = *(const bf16x8*)&Bs[s][wc * (NT * 16) + nt * 16 + l16][quad * 8];
#pragma unroll
      for (int mt = 0; mt < MT; ++mt)
#pragma unroll
        for (int nt = 0; nt < NT; ++nt)
          acc[mt][nt] =
              __builtin_amdgcn_mfma_f32_16x16x32_bf16(af[mt], bfr[nt], acc[mt][nt], 0, 0, 0);
    }
  }

#pragma unroll
  for (int mt = 0; mt < MT; ++mt) {
    const int row0 = bm0 + wr * (MT * 16) + mt * 16 + quad * 4;
#pragma unroll
    for (int nt = 0; nt < NT; ++nt) {
      const int col = bn0 + wc * (NT * 16) + nt * 16 + l16;
#pragma unroll
      for (int r = 0; r < 4; ++r) {
        float v = acc[mt][nt][r];
        if (RELU) v = fmaxf(v, 0.f);
        C[(size_t)(row0 + r) * N + col] = (__bf16)v;
      }
    }
  }
}

// ---------------------------------------------------------------------------
// Flash attention, no max-subtraction (|scores| ~ 1e-2: exp is safe):
//   O_part[split] = sum_chunks exp(Q Uc^T * scale) @ Uc ; l_part = row sums.
// 128 q-rows/block (wave owns 32 = 2 m-tiles); staged Un/Ut amortized over
// 2x MFMA. grid (32 q-tiles, 16 key-splits) = 512 blocks (2/CU), 4 chunks
// of 64 keys per split. 2 barriers/chunk (Ps is per-wave: no barrier).
// ---------------------------------------------------------------------------
__global__ __launch_bounds__(256) void flash_attn(const __bf16* __restrict__ Q,
                                                  const __bf16* __restrict__ Un_g,
                                                  const __bf16* __restrict__ Ut_g,
                                                  float* __restrict__ O_part,
                                                  float* __restrict__ l_part) {
  __shared__ __bf16 Un[64][136];    // [key][d]   stride 272 B -> 2-way banks
  __shared__ __bf16 Ut[128][72];    // [d][key]   stride 144 B
  __shared__ __bf16 Ps[4][32][72];  // per-wave P [qrow 0..31][key]
  const int tid  = threadIdx.x;
  const int w    = tid >> 6;
  const int lane = tid & 63;
  const int quad = lane >> 4;
  const int l16  = lane & 15;
  const int qrow0 = blockIdx.x * 128;
  const int split = blockIdx.y;
  const float scale = 0.08838834764831845f;  // 1/sqrt(128)

  bf16x8 aq[2][4];
#pragma unroll
  for (int mt = 0; mt < 2; ++mt)
#pragma unroll
    for (int c = 0; c < 4; ++c)
      aq[mt][c] = *(const bf16x8*)(Q + (size_t)(qrow0 + w * 32 + mt * 16 + l16) * 128 +
                                   c * 32 + quad * 8);

  floatx4 o[2][8];
#pragma unroll
  for (int mt = 0; mt < 2; ++mt)
#pragma unroll
    for (int t = 0; t < 8; ++t) o[mt][t] = (floatx4){0.f, 0.f, 0.f, 0.f};
  float lsum[2][4] = {{0.f, 0.f, 0.f, 0.f}, {0.f, 0.f, 0.f, 0.f}};

  for (int chunk = 0; chunk < 4; ++chunk) {
    const int key0 = (split * 4 + chunk) * 64;
    __syncthreads();  // staged buffers safe to overwrite
#pragma unroll
    for (int p = 0; p < 4; ++p) {
      int r = (tid >> 4) + p * 16;
      int c = (tid & 15) * 8;
      *(bf16x8*)&Un[r][c] = *(const bf16x8*)(Un_g + (size_t)(key0 + r) * 128 + c);
    }
#pragma unroll
    for (int p = 0; p < 4; ++p) {
      int d = (tid >> 3) + p * 32;
      int kk = (tid & 7) * 8;
      *(bf16x8*)&Ut[d][kk] = *(const bf16x8*)(Ut_g + (size_t)d * 4096 + key0 + kk);
    }
    __syncthreads();

    // S = Q Uc^T for both m-tiles (bk read once), exp fp32, P -> LDS bf16.
#pragma unroll
    for (int t = 0; t < 4; ++t) {
      bf16x8 bk[4];
#pragma unroll
      for (int c = 0; c < 4; ++c)
        bk[c] = *(const bf16x8*)&Un[t * 16 + l16][c * 32 + quad * 8];
      floatx4 s0 = (floatx4){0.f, 0.f, 0.f, 0.f};
      floatx4 s1 = (floatx4){0.f, 0.f, 0.f, 0.f};
#pragma unroll
      for (int c = 0; c < 4; ++c) {
        s0 = __builtin_amdgcn_mfma_f32_16x16x32_bf16(aq[0][c], bk[c], s0, 0, 0, 0);
        s1 = __builtin_amdgcn_mfma_f32_16x16x32_bf16(aq[1][c], bk[c], s1, 0, 0, 0);
      }
#pragma unroll
      for (int r = 0; r < 4; ++r) {
        float p0 = __expf(s0[r] * scale);
        float p1 = __expf(s1[r] * scale);
        lsum[0][r] += p0;
        lsum[1][r] += p1;
        Ps[w][quad * 4 + r][t * 16 + l16] = (__bf16)p0;
        Ps[w][16 + quad * 4 + r][t * 16 + l16] = (__bf16)p1;
      }
    }
    // Ps is per-wave: compiler's lgkmcnt ordering suffices, no barrier.

    // O += P @ Uc (bv read once per (c2,dt), used by both m-tiles)
#pragma unroll
    for (int c2 = 0; c2 < 2; ++c2) {
      bf16x8 ap0 = *(const bf16x8*)&Ps[w][l16][c2 * 32 + quad * 8];
      bf16x8 ap1 = *(const bf16x8*)&Ps[w][16 + l16][c2 * 32 + quad * 8];
#pragma unroll
      for (int dt = 0; dt < 8; ++dt) {
        bf16x8 bv = *(const bf16x8*)&Ut[dt * 16 + l16][c2 * 32 + quad * 8];
        o[0][dt] = __builtin_amdgcn_mfma_f32_16x16x32_bf16(ap0, bv, o[0][dt], 0, 0, 0);
        o[1][dt] = __builtin_amdgcn_mfma_f32_16x16x32_bf16(ap1, bv, o[1][dt], 0, 0, 0);
      }
    }
  }

  // Row sums: reduce over the 16 key-columns held across l16.
#pragma unroll
  for (int mt = 0; mt < 2; ++mt)
#pragma unroll
    for (int r = 0; r < 4; ++r) {
      float v = lsum[mt][r];
      v += __shfl_xor(v, 1);
      v += __shfl_xor(v, 2);
      v += __shfl_xor(v, 4);
      v += __shfl_xor(v, 8);
      lsum[mt][r] = v;
    }

  float* Ob = O_part + (size_t)split * 4096 * 128;
#pragma unroll
  for (int mt = 0; mt < 2; ++mt) {
    const int row0 = qrow0 + w * 32 + mt * 16 + quad * 4;
#pragma unroll
    for (int dt = 0; dt < 8; ++dt) {
#pragma unroll
      for (int r = 0; r < 4; ++r) {
        Ob[(size_t)(row0 + r) * 128 + dt * 16 + l16] = o[mt][dt][r];
      }
    }
    if (l16 == 0) {
#pragma unroll
      for (int r = 0; r < 4; ++r) l_part[split * 4096 + row0 + r] = lsum[mt][r];
    }
  }
}

// ---------------------------------------------------------------------------
// Combine 16 key-splits: out = (sum_s O_s) / (sum_s l_s)
// ---------------------------------------------------------------------------
__global__ void combine_kernel(const float* __restrict__ O_part,
                               const float* __restrict__ l_part,
                               float* __restrict__ out) {
  const int i = blockIdx.x * 256 + threadIdx.x;
  const int row = i >> 7;
  float num = 0.f, den = 0.f;
#pragma unroll
  for (int s = 0; s < 16; ++s) {
    num += O_part[(size_t)s * 524288 + i];
    den += l_part[s * 4096 + row];
  }
  out[i] = num / den;
}

extern "C" void kernel_launch(void* const* d_in, const int* in_sizes, int n_in,
                              void* d_out, int out_size, void* d_ws, size_t ws_size,
                              hipStream_t stream) {
  (void)in_sizes; (void)n_in; (void)out_size; (void)ws_size;
  const float* ctx      = (const float*)d_in[0];  // [4096,1024]
  const float* ent_embs = (const float*)d_in[1];  // [24636,128]
  const float* W1       = (const float*)d_in[2];  // [768,1024]
  const float* W2       = (const float*)d_in[3];  // [512,768]
  const float* W3       = (const float*)d_in[4];  // [128,512]
  const int*   ent_list = (const int*)d_in[5];    // [4096,50]
  float* out = (float*)d_out;

  // ws layout; peak use 57 MB (ws is 256 MB).
  char* base = (char*)d_ws;
  __bf16* user_n = (__bf16*)(base);                       // 1 MB
  __bf16* user_t = (__bf16*)(base + (1ull << 20));        // 1 MB
  __bf16* qb     = (__bf16*)(base + (2ull << 20));        // 1 MB
  float*  l_part = (float*)(base + (3ull << 20));         // 256 KB
  __bf16* ctxb   = (__bf16*)(base + (4ull << 20));        // 8 MB
  __bf16* W1b    = (__bf16*)(base + (12ull << 20));       // 1.5 MB
  __bf16* W2b    = (__bf16*)(base + 14155776ull);         // 13.5 MB, 0.75 MB
  __bf16* W3b    = (__bf16*)(base + 14942208ull);         // 14.25 MB, 128 KB
  __bf16* x1b    = (__bf16*)(base + (15ull << 20));       // 6 MB
  __bf16* x2b    = (__bf16*)(base + (21ull << 20));       // 4 MB
  float*  O_part = (float*)(base + (25ull << 20));        // 32 MB

  cvt_all_kernel<<<2656, 256, 0, stream>>>(ctx, ctxb, W1, W1b, W2, W2b, W3, W3b);
  pool_kernel<<<1024, 256, 0, stream>>>(ent_embs, ent_list, user_n);
  transpose_kernel<<<dim3(64, 2), 256, 0, stream>>>(user_n, user_t);

  // MLP: 128x96 / 128x64 / 32x64 tiles, relu+cvt fused in epilogue.
  gemm_bt<4, 1, 2, 6, 1><<<dim3(8, 32), 256, 0, stream>>>(ctxb, W1b, x1b, 4096, 768, 1024);
  gemm_bt<4, 1, 2, 4, 1><<<dim3(8, 32), 256, 0, stream>>>(x1b, W2b, x2b, 4096, 512, 768);
  gemm_bt<2, 2, 1, 2, 0><<<dim3(2, 128), 256, 0, stream>>>(x2b, W3b, qb, 4096, 128, 512);

  flash_attn<<<dim3(32, 16), 256, 0, stream>>>(qb, user_n, user_t, O_part, l_part);
  combine_kernel<<<2048, 256, 0, stream>>>(O_part, l_part, out);
}